// Round 8
// baseline (293.885 us; speedup 1.0000x reference)
//
#include <hip/hip_runtime.h>
#include <stdint.h>

typedef __attribute__((ext_vector_type(8))) short short8;
typedef __attribute__((ext_vector_type(4))) short short4v;
typedef __attribute__((ext_vector_type(4))) float f32x4;

__device__ __forceinline__ unsigned short f32_to_bf16(float f) {
    unsigned int u = __float_as_uint(f);
    u += 0x7FFFu + ((u >> 16) & 1u);   // round-to-nearest-even
    return (unsigned short)(u >> 16);
}

__device__ __forceinline__ short8 load8_f32_as_bf16(const float* __restrict__ ap) {
    f32x4 f0 = *(const f32x4*)ap;
    f32x4 f1 = *(const f32x4*)(ap + 4);
    union { short8 s; unsigned short u[8]; } cv;
#pragma unroll
    for (int t = 0; t < 4; ++t) {
        cv.u[t]     = f32_to_bf16(f0[t]);
        cv.u[t + 4] = f32_to_bf16(f1[t]);
    }
    return cv.s;
}

// async global->LDS DMA, 16B/lane; LDS dest = wave-uniform base + lane*16 (m104/m108)
__device__ __forceinline__ void gld_lds16(const void* g, void* l) {
    __builtin_amdgcn_global_load_lds(
        (const __attribute__((address_space(1))) unsigned int*)(unsigned long long)(uintptr_t)g,
        (__attribute__((address_space(3))) unsigned int*)(unsigned int)(uintptr_t)l,
        16, 0, 0);
}

// ---------------------------------------------------------------------------
// gemm128: single-buffered NT GEMM (m97 structure) -- QKV only (1536 blocks,
// 4-resident/CU, cross-block overlap hides barrier drain; measured 978 TF).
// SWIZ=6: z<2 -> q,k (m-chunk per XCD); z==2 -> vT swapped operands
// (n-chunk per XCD), C2/ldc2 output.
// ---------------------------------------------------------------------------
template<int EPI, int SWIZ, int MT>
__global__ __launch_bounds__(256, 4)
void gemm128(const unsigned short* __restrict__ A,
             int lda,
             const unsigned short* __restrict__ B, int ldb,
             void* __restrict__ C, int ldc, int K,
             long bStride, long cStride,
             void* __restrict__ C2, int ldc2)
{
    int z = blockIdx.z;
    int mblk, nblk;
    {
        int x = blockIdx.x, yy = blockIdx.y;
        if (z < 2) { mblk = x * 8 + (yy & 7); nblk = yy >> 3; }
        else       { nblk = x * 8 + (yy & 7); mblk = yy >> 3; }
    }
    int m0 = mblk * MT;
    int n0 = nblk * 128;

    const unsigned short* Ab;
    const unsigned short* Bb;
    if (z < 2) { Ab = A; Bb = B + (size_t)z * bStride; }
    else       { Ab = B + (size_t)2 * bStride; Bb = A; }

    __shared__ __align__(16) short As[MT * 64];
    __shared__ __align__(16) short Bs[128 * 64];

    int tid  = threadIdx.x;
    int lane = tid & 63, wid = tid >> 6;
    constexpr int MI = MT / 32;
    int wm = (wid & 1) * (MT / 2), wn = (wid >> 1) * 64;
    int fr = lane & 15, fq = lane >> 4;
    int sw0 = ((fq    ) ^ (fr & 7)) * 16;
    int sw1 = ((fq ^ 4) ^ (fr & 7)) * 16;

    int rS = tid >> 3;
    int cS = ((tid & 7) ^ (rS & 7)) * 8;
    char* AsB = (char*)As; char* BsB = (char*)Bs;

    f32x4 acc[MI][4];
#pragma unroll
    for (int i = 0; i < MI; ++i)
#pragma unroll
    for (int j = 0; j < 4; ++j) acc[i][j] = f32x4{0.f, 0.f, 0.f, 0.f};

    for (int k0 = 0; k0 < K; k0 += 64) {
        const unsigned short* pa = Ab + (size_t)(m0 + rS) * lda + k0 + cS;
        const unsigned short* pb = Bb + (size_t)(n0 + rS) * ldb + k0 + cS;
#pragma unroll
        for (int t = 0; t < MT / 32; ++t)
            gld_lds16(pa + (size_t)(32 * t) * lda, AsB + t * 4096 + tid * 16);
#pragma unroll
        for (int t = 0; t < 4; ++t)
            gld_lds16(pb + (size_t)(32 * t) * ldb,  BsB + t * 4096 + tid * 16);
        __syncthreads();

#pragma unroll
        for (int kh = 0; kh < 2; ++kh) {
            int sw = kh ? sw1 : sw0;
            short8 a[MI], b[4];
#pragma unroll
            for (int i = 0; i < MI; ++i)
                a[i] = *(const short8*)(AsB + (wm + i * 16 + fr) * 128 + sw);
#pragma unroll
            for (int j = 0; j < 4; ++j)
                b[j] = *(const short8*)(BsB + (wn + j * 16 + fr) * 128 + sw);
#pragma unroll
            for (int i = 0; i < MI; ++i)
#pragma unroll
            for (int j = 0; j < 4; ++j)
                acc[i][j] = __builtin_amdgcn_mfma_f32_16x16x32_bf16(a[i], b[j], acc[i][j], 0, 0, 0);
        }
        __syncthreads();
    }

    // epilogue: C/D layout col = lane&15, row = (lane>>4)*4 + reg [m89/m91]
    unsigned short* Cz; int ldcz;
    if (z >= 2) { Cz = (unsigned short*)C2; ldcz = ldc2; }
    else { Cz = (unsigned short*)C + (size_t)z * cStride; ldcz = ldc; }
#pragma unroll
    for (int i = 0; i < MI; ++i)
#pragma unroll
    for (int j = 0; j < 4; ++j)
#pragma unroll
    for (int r = 0; r < 4; ++r) {
        int row = m0 + wm + i * 16 + fq * 4 + r;
        int col = n0 + wn + j * 16 + fr;
        Cz[(size_t)row * ldcz + col] = f32_to_bf16(acc[i][j][r]);
    }
}

// ---------------------------------------------------------------------------
// gemm8p: 256x128-tile deep-pipelined NT GEMM, 8 waves (4M x 2N, 64x64/wave,
// acc 4x4), BK=64, 3-slot LDS ring (144 KB, 1 block/CU), counted vmcnt(6)
// gates (never 0 until tail), s_setprio around the MFMA cluster.
// MEASURED (R2 ledger): -17.6 us on MLP1+MLP2 vs the m97 structure at
// uniform 256-block (1/CU) grids. Fails only on ragged multi-round grids
// (R2's QKV 768@1/CU regressed) -- all call sites here are 1.0-1.13 rounds.
// Ring safety: slot staged for tile t+2 was read at t-1, whose ds_reads
// retired (lgkmcnt before MFMA) before the barrier preceding this STAGE.
// Gate ledger: 6 loads/thread/tile, 12 in flight; vmcnt(6) == "next tile
// landed". Prologue vmcnt(6) after staging 2 tiles. Requires NT >= 2.
// SWIZ: 1 = xcd-m-chunk, grid (8, NBm) with NBm%... (MLPs: (8,32))
//       5 = scores triangle over 256-row m-tiles: cum(i)=i(i+1), i in [0,8);
//           x -> (i, n), n-blocks 0..2i+1 (lower triangle). grid (72,1,4).
//       8 = PV decode, grid MUST be (8,8,4): p=blockIdx.x (xcd), s=z*8+y:
//           n=s>>2, z=2*(p&1)+(s&1), m=((s>>1)&1)?7-(p>>1):(p>>1).
//           Bijective (verified); per-XCD NT sum = 576 const; each XCD
//           touches one z-pair's vT slices.
// EPI: 2 relu(+bias[col]) bf16 | 3 +bias[col] fp32 | 4 /rsum[row] bf16 |
//      6 exp(v*scale-16) masked col<=row bf16 + atomicAdd rowsums
// AMODE 2: A->A2 at k>=ksplit (MLP1 concat). KLIMIT: kend=min(K,m0+256)
// (PV only: covers exactly the S col-blocks j<=2i+1 that scores wrote).
// ---------------------------------------------------------------------------
template<int AMODE, int EPI, int SWIZ, bool KLIMIT>
__global__ __launch_bounds__(512, 2)
void gemm8p(const unsigned short* __restrict__ A, const unsigned short* __restrict__ A2,
            int lda, int lda2, int ksplit,
            const unsigned short* __restrict__ B, int ldb,
            void* __restrict__ C, int ldc, int K,
            long aStride, long bStride, long cStride,
            const float* __restrict__ bias, long biasStride, float scale)
{
    int z = blockIdx.z;
    int mblk, nblk;
    if (SWIZ == 1) {
        int lin = blockIdx.y * gridDim.x + blockIdx.x;
        int xcd = lin & 7, idx = lin >> 3;
        int mch = (int)gridDim.y >> 3;       // (8,32) -> 4 m-tiles per XCD
        mblk = xcd * mch + idx % mch;
        nblk = idx / mch;
    } else if (SWIZ == 5) {
        int x = blockIdx.x;                  // [0,72)
        int i = 0;
        while (i < 7 && (i + 1) * (i + 2) <= x) ++i;   // cum(i)=i(i+1)
        mblk = i;
        nblk = x - i * (i + 1);              // [0, 2i+2)
    } else if (SWIZ == 8) {
        int p = blockIdx.x;                  // == glin&7 (x fastest)
        int s = (int)blockIdx.z * 8 + (int)blockIdx.y;   // [0,32)
        nblk = s >> 2;
        int msel = (s >> 1) & 1, zsel = s & 1;
        z    = 2 * (p & 1) + zsel;
        mblk = msel ? 7 - (p >> 1) : (p >> 1);
    } else {
        mblk = blockIdx.y;
        nblk = blockIdx.x;
    }
    int m0 = mblk * 256, n0 = nblk * 128;

    const unsigned short* Ab = A + (size_t)z * aStride;
    const unsigned short* Bb = B + (size_t)z * bStride;

    constexpr int TILE = 49152;              // 32K A + 16K B per ring slot
    __shared__ __align__(16) char lds[3 * TILE];   // 144 KB

    int tid  = threadIdx.x;
    int lane = tid & 63, wid = tid >> 6;
    int wm = (wid & 3) * 64, wn = (wid >> 2) * 64;
    int fr = lane & 15, fq = lane >> 4;
    int sw0 = ((fq    ) ^ (fr & 7)) * 16;
    int sw1 = ((fq ^ 4) ^ (fr & 7)) * 16;

    // staging: thread covers rows rS + 64u, pre-swizzled source chunk so the
    // linear LDS dest (base + tid*16) realizes slot = chunk ^ (row&7)
    int rS = tid >> 3;                       // 0..63
    int cS = ((tid & 7) ^ (rS & 7)) * 8;

    int kend = KLIMIT ? min(K, m0 + 256) : K;
    int NT = kend >> 6;                      // >= 4 at all call sites

    f32x4 acc[4][4];
#pragma unroll
    for (int i = 0; i < 4; ++i)
#pragma unroll
    for (int j = 0; j < 4; ++j) acc[i][j] = f32x4{0.f, 0.f, 0.f, 0.f};

    auto STAGE = [&](int t, int slot) {      // 6 gld_lds per thread
        int k0 = t << 6;
        char* dst = lds + slot * TILE;
        const unsigned short* Asrc = Ab; int koff = k0, ldax = lda;
        if (AMODE == 2 && k0 >= ksplit) { Asrc = A2; koff = k0 - ksplit; ldax = lda2; }
        const unsigned short* pa = Asrc + (size_t)(m0 + rS) * ldax + koff + cS;
        const unsigned short* pb = Bb   + (size_t)(n0 + rS) * ldb  + k0   + cS;
#pragma unroll
        for (int u = 0; u < 4; ++u)
            gld_lds16(pa + (size_t)(64 * u) * ldax, dst + u * 8192 + tid * 16);
#pragma unroll
        for (int u = 0; u < 2; ++u)
            gld_lds16(pb + (size_t)(64 * u) * ldb, dst + 32768 + u * 8192 + tid * 16);
    };

    // prologue: 2 tiles in flight, wait only for tile 0 (oldest 6 of 12)
    STAGE(0, 0);
    STAGE(1, 1);
    asm volatile("s_waitcnt vmcnt(6)" ::: "memory");
    __builtin_amdgcn_s_barrier();
    __builtin_amdgcn_sched_barrier(0);
    asm volatile("" ::: "memory");

    int sc = 0, ss = 2;                      // compute slot, stage slot
    for (int t = 0; t < NT; ++t) {
        if (t + 2 < NT) STAGE(t + 2, ss);    // slot staged == slot read at t-1
        const char* AsB = (const char*)(lds + sc * TILE);
        const char* BsB = AsB + 32768;
#pragma unroll
        for (int kh = 0; kh < 2; ++kh) {
            int sw = kh ? sw1 : sw0;
            short8 a[4], b[4];
#pragma unroll
            for (int i = 0; i < 4; ++i)
                a[i] = *(const short8*)(AsB + (wm + i * 16 + fr) * 128 + sw);
#pragma unroll
            for (int j = 0; j < 4; ++j)
                b[j] = *(const short8*)(BsB + (wn + j * 16 + fr) * 128 + sw);
            __builtin_amdgcn_s_setprio(1);
#pragma unroll
            for (int i = 0; i < 4; ++i)
#pragma unroll
            for (int j = 0; j < 4; ++j)
                acc[i][j] = __builtin_amdgcn_mfma_f32_16x16x32_bf16(a[i], b[j], acc[i][j], 0, 0, 0);
            __builtin_amdgcn_s_setprio(0);
        }
        if (t + 1 < NT) {
            if (t + 2 < NT) { asm volatile("s_waitcnt vmcnt(6)" ::: "memory"); }
            else            { asm volatile("s_waitcnt vmcnt(0)" ::: "memory"); }
            __builtin_amdgcn_s_barrier();
            __builtin_amdgcn_sched_barrier(0);
            asm volatile("" ::: "memory");
        }
        sc = sc == 2 ? 0 : sc + 1;
        ss = ss == 2 ? 0 : ss + 1;
    }

    // epilogue: C/D layout col = lane&15, row = (lane>>4)*4 + reg [m89/m91]
    if (EPI == 6) {
        unsigned short* Cz = (unsigned short*)C + (size_t)z * cStride;
        float* rs = const_cast<float*>(bias) + z * biasStride;
#pragma unroll
        for (int i = 0; i < 4; ++i)
#pragma unroll
        for (int r = 0; r < 4; ++r) {
            int row = m0 + wm + i * 16 + fq * 4 + r;
            float s = 0.f;
#pragma unroll
            for (int j = 0; j < 4; ++j) {
                int col = n0 + wn + j * 16 + fr;
                float e = (col <= row) ? __expf(acc[i][j][r] * scale - 16.f) : 0.f;
                s += e;
                Cz[(size_t)row * ldc + col] = f32_to_bf16(e);
            }
            s += __shfl_xor(s, 1);
            s += __shfl_xor(s, 2);
            s += __shfl_xor(s, 4);
            s += __shfl_xor(s, 8);      // reduced over the 16 fr-lanes
            if (fr == 0) atomicAdd(&rs[row], s);
        }
    } else if (EPI == 4) {
        unsigned short* Cz = (unsigned short*)C + (size_t)z * cStride;
#pragma unroll
        for (int i = 0; i < 4; ++i)
#pragma unroll
        for (int r = 0; r < 4; ++r) {
            int row = m0 + wm + i * 16 + fq * 4 + r;
            float inv = 1.f / bias[z * biasStride + row];
#pragma unroll
            for (int j = 0; j < 4; ++j) {
                int col = n0 + wn + j * 16 + fr;
                Cz[(size_t)row * ldc + col] = f32_to_bf16(acc[i][j][r] * inv);
            }
        }
    } else {
#pragma unroll
        for (int i = 0; i < 4; ++i)
#pragma unroll
        for (int j = 0; j < 4; ++j)
#pragma unroll
        for (int r = 0; r < 4; ++r) {
            int row = m0 + wm + i * 16 + fq * 4 + r;
            int col = n0 + wn + j * 16 + fr;
            float v = acc[i][j][r];
            if (EPI == 2) {
                v += bias[col];
                v = v > 0.f ? v : 0.f;
                ((unsigned short*)C)[(size_t)row * ldc + col] = f32_to_bf16(v);
            } else {   // 3: fp32 + bias
                ((float*)C)[(size_t)row * ldc + col] = v + bias[col];
            }
        }
    }
}

// ---------------------------------------------------------------------------
// prep (R6, measured good): 64x64 transpose tiles, f32x4 loads / short4
// stores; 32-elems/thread xb convert. 2564 blocks.
// ---------------------------------------------------------------------------
__device__ __forceinline__ void transpose_tile64(const float* __restrict__ in,
                                                 unsigned short* __restrict__ out,
                                                 int rows, int cols, int bx, int by, int tid)
{
    __shared__ float t[64][65];
    int tx = tid & 15, ty = tid >> 4;   // 16 x 16
    int r0 = by * 64, c0 = bx * 64;
#pragma unroll
    for (int i = 0; i < 4; ++i) {
        f32x4 v = *(const f32x4*)(in + (size_t)(r0 + ty + i * 16) * cols + c0 + tx * 4);
#pragma unroll
        for (int j = 0; j < 4; ++j) t[ty + i * 16][tx * 4 + j] = v[j];
    }
    __syncthreads();
#pragma unroll
    for (int i = 0; i < 4; ++i) {
        union { short4v s; unsigned short u[4]; } o;
#pragma unroll
        for (int j = 0; j < 4; ++j) o.u[j] = f32_to_bf16(t[tx * 4 + j][ty + i * 16]);
        *(short4v*)(out + (size_t)(c0 + ty + i * 16) * rows + r0 + tx * 4) = o.s;
    }
}

__global__ __launch_bounds__(256)
void prep_kernel(const float* __restrict__ x,
                 const float* __restrict__ Wq, const float* __restrict__ Wk,
                 const float* __restrict__ Wv, const float* __restrict__ W1,
                 const float* __restrict__ W2,
                 unsigned short* __restrict__ xb, unsigned short* __restrict__ WT,
                 unsigned short* __restrict__ W1T, unsigned short* __restrict__ W2T,
                 float* __restrict__ rsum)
{
    int idx = blockIdx.x;
    int tid = threadIdx.x;
    if (idx < 1024) {
#pragma unroll
        for (int it = 0; it < 4; ++it) {
            size_t i = ((size_t)idx * 4 + it) * 2048 + (size_t)tid * 8;
            *(short8*)(xb + i) = load8_f32_as_bf16(x + i);
        }
    } else if (idx < 1792) {
        int t = idx - 1024;
        int w = t >> 8; t &= 255;
        const float* in = w == 0 ? Wq : (w == 1 ? Wk : Wv);
        transpose_tile64(in, WT + (size_t)w * 1024 * 1024, 1024, 1024,
                         t & 15, t >> 4, tid);
    } else if (idx < 2304) {
        int t = idx - 1792;                  // 512 tiles: 32 row-tiles x 16
        transpose_tile64(W1, W1T, 2048, 1024, t & 15, t >> 4, tid);
    } else if (idx < 2560) {
        int t = idx - 2304;                  // 256 tiles
        transpose_tile64(W2, W2T, 1024, 1024, t & 15, t >> 4, tid);
    } else {
        int t = idx - 2560;
        f32x4 zero = {0.f, 0.f, 0.f, 0.f};
        float* p = rsum + ((size_t)t * 256 + tid) * 8;
        *(f32x4*)p = zero;
        *(f32x4*)(p + 4) = zero;
    }
}

// ---------------------------------------------------------------------------
extern "C" void kernel_launch(void* const* d_in, const int* in_sizes, int n_in,
                              void* d_out, int out_size, void* d_ws, size_t ws_size,
                              hipStream_t stream)
{
    const float* x  = (const float*)d_in[0];   // [8192,1024]
    const float* Wq = (const float*)d_in[1];
    const float* Wk = (const float*)d_in[2];
    const float* Wv = (const float*)d_in[3];
    const float* W1 = (const float*)d_in[4];   // [2048,1024]
    const float* b1 = (const float*)d_in[5];
    const float* W2 = (const float*)d_in[6];   // [1024,1024]
    const float* b2 = (const float*)d_in[7];
    float* out = (float*)d_out;                // [8192,1024] fp32

    size_t off = 0;
    auto alloc = [&](size_t bytes) {
        char* r = (char*)d_ws + off;
        off += (bytes + 255) & ~(size_t)255;
        return r;
    };
    const size_t TOK = (size_t)8192 * 1024;    // tokens x dim
    unsigned short* WT   = (unsigned short*)alloc((size_t)3072 * 1024 * 2);
    unsigned short* W1T  = (unsigned short*)alloc((size_t)1024 * 2048 * 2);
    unsigned short* W2T  = (unsigned short*)alloc((size_t)1024 * 1024 * 2);
    unsigned short* xb   = (unsigned short*)alloc(TOK * 2);
    unsigned short* vT   = (unsigned short*)alloc((size_t)1024 * 8192 * 2); // [d][b*2048+s]
    unsigned short* attn = (unsigned short*)alloc(TOK * 2);
    float*          rsum = (float*)         alloc((size_t)4 * 2048 * 4);
    unsigned short* q    = (unsigned short*)alloc(TOK * 2);
    unsigned short* k    = (unsigned short*)alloc(TOK * 2);
    unsigned short* S    = (unsigned short*)alloc((size_t)4 * 2048 * 2048 * 2);
    unsigned short* h1   = S;                  // S dead after PV; MLP1 out aliases it
    // peak ws use: ~131 MB

    // prep: xb, WT, W1T, W2T, rsum=0 in one launch (2564 blocks, vectorized)
    prep_kernel<<<2564, 256, 0, stream>>>(x, Wq, Wk, Wv, W1, W2, xb, WT, W1T, W2T, rsum);

    // fused q,k,vT (z<2: q,k = xb @ Wqk^T m-chunked; z==2: vT = WvT @ xb^T
    // n-chunked). 1536 blocks, 4/CU. Measured 52-54 us / ~970 TF.
    gemm128<0, 6, 128><<<dim3(8, 64, 3), 256, 0, stream>>>(
        xb, 1024, WT, 1024, q, 1024, 1024,
        (long)1024 * 1024, (long)TOK, vT, 8192);

    // scores+softmax fused on 256-row m-tiles: P = exp(q@k^T/32 - 16)
    // (causal), rowsums -> rsum. Triangle: 72 blocks/z x 4 = 288 (~1.1/CU),
    // uniform K=1024 (NT=16). gemm8p ring pipeline.
    gemm8p<0, 6, 5, false><<<dim3(72, 1, 4), 512, 0, stream>>>(
        q, nullptr, 1024, 0, 0, k, 1024, S, 2048, 1024,
        (long)2048 * 1024, (long)2048 * 1024, (long)2048 * 2048,
        rsum, 2048, 0.03125f);

    // attn = (P @ v) / rsum[row]: 256-row tiles, kend=m0+256, SWIZ=8 decode
    // (grid (8,8,4) = 256 blocks = 1/CU exact, per-XCD NT balanced).
    gemm8p<0, 4, 8, true><<<dim3(8, 8, 4), 512, 0, stream>>>(
        S, nullptr, 2048, 0, 0, vT, 8192, attn, 1024, 2048,
        (long)2048 * 2048, (long)2048, (long)2048 * 1024,
        rsum, 2048, 0.f);

    // MLP1: h1 = relu([attn | x] @ W1 + b1), split-A concat trick.
    // 256 blocks = 1/CU exact, K=2048. (R2-measured config: -17.6 us combo.)
    gemm8p<2, 2, 1, false><<<dim3(8, 32, 1), 512, 0, stream>>>(
        attn, xb, 1024, 1024, 1024, W1T, 2048, h1, 1024, 2048,
        0, 0, 0, b1, 0, 0.f);

    // MLP2: out = h1 @ W2 + b2 (fp32 to d_out), 256 blocks = 1/CU exact.
    gemm8p<0, 3, 1, false><<<dim3(8, 32, 1), 512, 0, stream>>>(
        h1, nullptr, 1024, 0, 0, W2T, 1024, out, 1024, 1024,
        0, 0, 0, b2, 0, 0.f);
}

// Round 9
// 285.409 us; speedup vs baseline: 1.0297x; 1.0297x over previous
//
#include <hip/hip_runtime.h>
#include <stdint.h>

typedef __attribute__((ext_vector_type(8))) short short8;
typedef __attribute__((ext_vector_type(4))) short short4v;
typedef __attribute__((ext_vector_type(4))) float f32x4;

__device__ __forceinline__ unsigned short f32_to_bf16(float f) {
    unsigned int u = __float_as_uint(f);
    u += 0x7FFFu + ((u >> 16) & 1u);   // round-to-nearest-even
    return (unsigned short)(u >> 16);
}

__device__ __forceinline__ short8 load8_f32_as_bf16(const float* __restrict__ ap) {
    f32x4 f0 = *(const f32x4*)ap;
    f32x4 f1 = *(const f32x4*)(ap + 4);
    union { short8 s; unsigned short u[8]; } cv;
#pragma unroll
    for (int t = 0; t < 4; ++t) {
        cv.u[t]     = f32_to_bf16(f0[t]);
        cv.u[t + 4] = f32_to_bf16(f1[t]);
    }
    return cv.s;
}

// async global->LDS DMA, 16B/lane; LDS dest = wave-uniform base + lane*16 (m104/m108)
__device__ __forceinline__ void gld_lds16(const void* g, void* l) {
    __builtin_amdgcn_global_load_lds(
        (const __attribute__((address_space(1))) unsigned int*)(unsigned long long)(uintptr_t)g,
        (__attribute__((address_space(3))) unsigned int*)(unsigned int)(uintptr_t)l,
        16, 0, 0);
}

// ---------------------------------------------------------------------------
// gemm128: single-buffered NT GEMM (m97 structure) -- QKV only (1536 blocks,
// 4-resident/CU, cross-block overlap hides barrier drain; measured 53.3 us
// ~= 970 TF in R8 trimmed form). z<2 -> q,k (m-chunk per XCD); z==2 -> vT
// swapped operands (n-chunk per XCD), C2/ldc2 output.
// ---------------------------------------------------------------------------
template<int MT>
__global__ __launch_bounds__(256, 4)
void gemm128(const unsigned short* __restrict__ A,
             int lda,
             const unsigned short* __restrict__ B, int ldb,
             void* __restrict__ C, int ldc, int K,
             long bStride, long cStride,
             void* __restrict__ C2, int ldc2)
{
    int z = blockIdx.z;
    int mblk, nblk;
    {
        int x = blockIdx.x, yy = blockIdx.y;
        if (z < 2) { mblk = x * 8 + (yy & 7); nblk = yy >> 3; }
        else       { nblk = x * 8 + (yy & 7); mblk = yy >> 3; }
    }
    int m0 = mblk * MT;
    int n0 = nblk * 128;

    const unsigned short* Ab;
    const unsigned short* Bb;
    if (z < 2) { Ab = A; Bb = B + (size_t)z * bStride; }
    else       { Ab = B + (size_t)2 * bStride; Bb = A; }

    __shared__ __align__(16) short As[MT * 64];
    __shared__ __align__(16) short Bs[128 * 64];

    int tid  = threadIdx.x;
    int lane = tid & 63, wid = tid >> 6;
    constexpr int MI = MT / 32;
    int wm = (wid & 1) * (MT / 2), wn = (wid >> 1) * 64;
    int fr = lane & 15, fq = lane >> 4;
    int sw0 = ((fq    ) ^ (fr & 7)) * 16;
    int sw1 = ((fq ^ 4) ^ (fr & 7)) * 16;

    int rS = tid >> 3;
    int cS = ((tid & 7) ^ (rS & 7)) * 8;
    char* AsB = (char*)As; char* BsB = (char*)Bs;

    f32x4 acc[MI][4];
#pragma unroll
    for (int i = 0; i < MI; ++i)
#pragma unroll
    for (int j = 0; j < 4; ++j) acc[i][j] = f32x4{0.f, 0.f, 0.f, 0.f};

    for (int k0 = 0; k0 < K; k0 += 64) {
        const unsigned short* pa = Ab + (size_t)(m0 + rS) * lda + k0 + cS;
        const unsigned short* pb = Bb + (size_t)(n0 + rS) * ldb + k0 + cS;
#pragma unroll
        for (int t = 0; t < MT / 32; ++t)
            gld_lds16(pa + (size_t)(32 * t) * lda, AsB + t * 4096 + tid * 16);
#pragma unroll
        for (int t = 0; t < 4; ++t)
            gld_lds16(pb + (size_t)(32 * t) * ldb,  BsB + t * 4096 + tid * 16);
        __syncthreads();

#pragma unroll
        for (int kh = 0; kh < 2; ++kh) {
            int sw = kh ? sw1 : sw0;
            short8 a[MI], b[4];
#pragma unroll
            for (int i = 0; i < MI; ++i)
                a[i] = *(const short8*)(AsB + (wm + i * 16 + fr) * 128 + sw);
#pragma unroll
            for (int j = 0; j < 4; ++j)
                b[j] = *(const short8*)(BsB + (wn + j * 16 + fr) * 128 + sw);
#pragma unroll
            for (int i = 0; i < MI; ++i)
#pragma unroll
            for (int j = 0; j < 4; ++j)
                acc[i][j] = __builtin_amdgcn_mfma_f32_16x16x32_bf16(a[i], b[j], acc[i][j], 0, 0, 0);
        }
        __syncthreads();
    }

    // epilogue: C/D layout col = lane&15, row = (lane>>4)*4 + reg [m89/m91]
    unsigned short* Cz; int ldcz;
    if (z >= 2) { Cz = (unsigned short*)C2; ldcz = ldc2; }
    else { Cz = (unsigned short*)C + (size_t)z * cStride; ldcz = ldc; }
#pragma unroll
    for (int i = 0; i < MI; ++i)
#pragma unroll
    for (int j = 0; j < 4; ++j)
#pragma unroll
    for (int r = 0; r < 4; ++r) {
        int row = m0 + wm + i * 16 + fq * 4 + r;
        int col = n0 + wn + j * 16 + fr;
        Cz[(size_t)row * ldcz + col] = f32_to_bf16(acc[i][j][r]);
    }
}

// ---------------------------------------------------------------------------
// gemmdb: double-buffered NT GEMM (R7 config, measured best total 287.5) --
// scores and PV. MT=128, BK=64, 4 waves, LDS 64 KB (2 buf), counted
// vmcnt(8) gate (drains to 0 only at the tail).
// SWIZ: 5 = triangular causal (136/z) with xcd pre-permute x'=(x%8)*17+x/8
//       7 = PV decode, grid MUST be (8,16,4): xcd=glin%8, z=xcd>>1
//           (vT slice per xcd-pair L2), balanced m-sets.
// EPI: 4 /rsum[row] bf16 | 6 exp(v*scale-16) masked col<=row bf16 +
//      atomicAdd rowsums. KLIMIT: kend = min(K, m0+128).
// ---------------------------------------------------------------------------
template<int EPI, int SWIZ, bool KLIMIT>
__global__ __launch_bounds__(256, 2)
void gemmdb(const unsigned short* __restrict__ A,
            int lda,
            const unsigned short* __restrict__ B, int ldb,
            void* __restrict__ C, int ldc, int K,
            long aStride, long bStride, long cStride,
            const float* __restrict__ bias, long biasStride, float scale)
{
    int z = blockIdx.z;
    int mblk, nblk;
    if (SWIZ == 5) {
        // xcd pre-permute then triangle decode (i in [0,16))
        int x = blockIdx.x;
        int per = (int)gridDim.x >> 3;        // 136/8 = 17
        x = (x & 7) * per + (x >> 3);
        int a = (int)sqrtf(2.f * (float)x + 1.f);
        if (a > 15) a = 15;
        while (a < 15 && ((a + 1) * (a + 2) / 2) <= x) ++a;
        while (a > 0 && (a * (a + 1) / 2) > x) --a;
        mblk = a;
        nblk = x - a * (a + 1) / 2;
    } else if (SWIZ == 7) {
        int glin = (int)blockIdx.z * 128 + (int)blockIdx.y * 8 + (int)blockIdx.x;
        int xcd = glin & 7;
        int s   = glin >> 3;                  // [0,64) per xcd
        z = xcd >> 1;                         // batch owned by this xcd pair
        int h  = xcd & 1;
        int jm = s & 7;
        nblk   = s >> 3;                      // [0,8)
        mblk   = (jm & 1) ? (15 - h - (jm >> 1) * 2) : ((jm >> 1) * 2 + h);
    } else {
        mblk = blockIdx.y;
        nblk = blockIdx.x;
    }
    int m0 = mblk * 128;
    int n0 = nblk * 128;

    const unsigned short* Ab = A + (size_t)z * aStride;
    const unsigned short* Bb = B + (size_t)z * bStride;

    __shared__ __align__(16) char lds[65536];   // 2 x [A 16K | B 16K]

    int tid  = threadIdx.x;
    int lane = tid & 63, wid = tid >> 6;
    int wm = (wid & 1) * 64, wn = (wid >> 1) * 64;
    int fr = lane & 15, fq = lane >> 4;
    int sw0 = ((fq    ) ^ (fr & 7)) * 16;
    int sw1 = ((fq ^ 4) ^ (fr & 7)) * 16;

    int rS = tid >> 3;                       // 0..31
    int cS = ((tid & 7) ^ (rS & 7)) * 8;     // swizzled source chunk (k elems)

    int kend = KLIMIT ? min(K, m0 + 128) : K;
    int NT = kend >> 6;                      // >= 1 at all call sites

    f32x4 acc[4][4];
#pragma unroll
    for (int i = 0; i < 4; ++i)
#pragma unroll
    for (int j = 0; j < 4; ++j) acc[i][j] = f32x4{0.f, 0.f, 0.f, 0.f};

    auto STAGE = [&](int kt) {               // 8 gld_lds per thread
        char* dst = lds + (kt & 1) * 32768;
        const unsigned short* pa = Ab + (size_t)(m0 + rS) * lda + (kt << 6) + cS;
        const unsigned short* pb = Bb + (size_t)(n0 + rS) * ldb + (kt << 6) + cS;
#pragma unroll
        for (int u = 0; u < 4; ++u)
            gld_lds16(pa + (size_t)(32 * u) * lda, dst + u * 4096 + tid * 16);
#pragma unroll
        for (int u = 0; u < 4; ++u)
            gld_lds16(pb + (size_t)(32 * u) * ldb, dst + 16384 + u * 4096 + tid * 16);
    };

    STAGE(0);
    for (int t = 0; t < NT; ++t) {
        if (t + 1 < NT) {
            STAGE(t + 1);                    // 16 outstanding; wait oldest 8
            asm volatile("s_waitcnt vmcnt(8)" ::: "memory");
        } else {
            asm volatile("s_waitcnt vmcnt(0)" ::: "memory");
        }
        __builtin_amdgcn_s_barrier();        // all waves' tile-t loads landed
        __builtin_amdgcn_sched_barrier(0);
        const char* AsB = (const char*)lds + (t & 1) * 32768;
        const char* BsB = AsB + 16384;
#pragma unroll
        for (int kh = 0; kh < 2; ++kh) {
            int sw = kh ? sw1 : sw0;
            short8 a[4], b[4];
#pragma unroll
            for (int i = 0; i < 4; ++i)
                a[i] = *(const short8*)(AsB + (wm + i * 16 + fr) * 128 + sw);
#pragma unroll
            for (int j = 0; j < 4; ++j)
                b[j] = *(const short8*)(BsB + (wn + j * 16 + fr) * 128 + sw);
            __builtin_amdgcn_s_setprio(1);
#pragma unroll
            for (int i = 0; i < 4; ++i)
#pragma unroll
            for (int j = 0; j < 4; ++j)
                acc[i][j] = __builtin_amdgcn_mfma_f32_16x16x32_bf16(a[i], b[j], acc[i][j], 0, 0, 0);
            __builtin_amdgcn_s_setprio(0);
        }
        __builtin_amdgcn_s_barrier();        // WAR: next iter stages this buf
        __builtin_amdgcn_sched_barrier(0);
        asm volatile("" ::: "memory");
    }

    // epilogue: C/D layout col = lane&15, row = (lane>>4)*4 + reg [m89/m91]
    if (EPI == 6) {
        unsigned short* Cz = (unsigned short*)C + (size_t)z * cStride;
        float* rs = const_cast<float*>(bias) + z * biasStride;
#pragma unroll
        for (int i = 0; i < 4; ++i)
#pragma unroll
        for (int r = 0; r < 4; ++r) {
            int row = m0 + wm + i * 16 + fq * 4 + r;
            float s = 0.f;
#pragma unroll
            for (int j = 0; j < 4; ++j) {
                int col = n0 + wn + j * 16 + fr;
                float e = (col <= row) ? __expf(acc[i][j][r] * scale - 16.f) : 0.f;
                s += e;
                Cz[(size_t)row * ldc + col] = f32_to_bf16(e);
            }
            s += __shfl_xor(s, 1);
            s += __shfl_xor(s, 2);
            s += __shfl_xor(s, 4);
            s += __shfl_xor(s, 8);      // reduced over the 16 fr-lanes
            if (fr == 0) atomicAdd(&rs[row], s);
        }
    } else {   // EPI == 4: divide by softmax rowsum
        unsigned short* Cz = (unsigned short*)C + (size_t)z * cStride;
#pragma unroll
        for (int i = 0; i < 4; ++i)
#pragma unroll
        for (int r = 0; r < 4; ++r) {
            int row = m0 + wm + i * 16 + fq * 4 + r;
            float inv = 1.f / bias[z * biasStride + row];
#pragma unroll
            for (int j = 0; j < 4; ++j) {
                int col = n0 + wn + j * 16 + fr;
                Cz[(size_t)row * ldc + col] = f32_to_bf16(acc[i][j][r] * inv);
            }
        }
    }
}

// ---------------------------------------------------------------------------
// gemm8p: 256x128-tile ring-pipelined NT GEMM (3-slot LDS ring, 144 KB,
// 8 waves, counted vmcnt(6)) -- MLPs ONLY. R2 ledger: -17.6 us on MLP1+MLP2
// vs the m97 structure, at uniform-K exactly-1-round 256-block grids (its
// only proven regime; it loses on ragged/non-uniform grids: R2-QKV, R8-
// scores/PV). SWIZ=1 xcd-m-chunk. EPI 2 relu(+bias) bf16 | 3 +bias fp32.
// AMODE 2: A->A2 at k>=ksplit (MLP1 concat). Requires NT >= 2.
// ---------------------------------------------------------------------------
template<int AMODE, int EPI>
__global__ __launch_bounds__(512, 2)
void gemm8p(const unsigned short* __restrict__ A, const unsigned short* __restrict__ A2,
            int lda, int lda2, int ksplit,
            const unsigned short* __restrict__ B, int ldb,
            void* __restrict__ C, int ldc, int K,
            const float* __restrict__ bias)
{
    int lin = blockIdx.y * gridDim.x + blockIdx.x;
    int xcd = lin & 7, idx = lin >> 3;
    int mch = (int)gridDim.y >> 3;           // (8,32) -> 4 m-tiles per XCD
    int mblk = xcd * mch + idx % mch;
    int nblk = idx / mch;
    int m0 = mblk * 256, n0 = nblk * 128;

    constexpr int TILE = 49152;              // 32K A + 16K B per ring slot
    __shared__ __align__(16) char lds[3 * TILE];   // 144 KB

    int tid  = threadIdx.x;
    int lane = tid & 63, wid = tid >> 6;
    int wm = (wid & 3) * 64, wn = (wid >> 2) * 64;
    int fr = lane & 15, fq = lane >> 4;
    int sw0 = ((fq    ) ^ (fr & 7)) * 16;
    int sw1 = ((fq ^ 4) ^ (fr & 7)) * 16;

    int rS = tid >> 3;                       // 0..63
    int cS = ((tid & 7) ^ (rS & 7)) * 8;

    int NT = K >> 6;                         // 16 or 32 here

    f32x4 acc[4][4];
#pragma unroll
    for (int i = 0; i < 4; ++i)
#pragma unroll
    for (int j = 0; j < 4; ++j) acc[i][j] = f32x4{0.f, 0.f, 0.f, 0.f};

    auto STAGE = [&](int t, int slot) {      // 6 gld_lds per thread
        int k0 = t << 6;
        char* dst = lds + slot * TILE;
        const unsigned short* Asrc = A; int koff = k0, ldax = lda;
        if (AMODE == 2 && k0 >= ksplit) { Asrc = A2; koff = k0 - ksplit; ldax = lda2; }
        const unsigned short* pa = Asrc + (size_t)(m0 + rS) * ldax + koff + cS;
        const unsigned short* pb = B    + (size_t)(n0 + rS) * ldb  + k0   + cS;
#pragma unroll
        for (int u = 0; u < 4; ++u)
            gld_lds16(pa + (size_t)(64 * u) * ldax, dst + u * 8192 + tid * 16);
#pragma unroll
        for (int u = 0; u < 2; ++u)
            gld_lds16(pb + (size_t)(64 * u) * ldb, dst + 32768 + u * 8192 + tid * 16);
    };

    // prologue: 2 tiles in flight, wait only for tile 0 (oldest 6 of 12)
    STAGE(0, 0);
    STAGE(1, 1);
    asm volatile("s_waitcnt vmcnt(6)" ::: "memory");
    __builtin_amdgcn_s_barrier();
    __builtin_amdgcn_sched_barrier(0);
    asm volatile("" ::: "memory");

    int sc = 0, ss = 2;                      // compute slot, stage slot
    for (int t = 0; t < NT; ++t) {
        if (t + 2 < NT) STAGE(t + 2, ss);    // slot staged == slot read at t-1
        const char* AsB = (const char*)(lds + sc * TILE);
        const char* BsB = AsB + 32768;
#pragma unroll
        for (int kh = 0; kh < 2; ++kh) {
            int sw = kh ? sw1 : sw0;
            short8 a[4], b[4];
#pragma unroll
            for (int i = 0; i < 4; ++i)
                a[i] = *(const short8*)(AsB + (wm + i * 16 + fr) * 128 + sw);
#pragma unroll
            for (int j = 0; j < 4; ++j)
                b[j] = *(const short8*)(BsB + (wn + j * 16 + fr) * 128 + sw);
            __builtin_amdgcn_s_setprio(1);
#pragma unroll
            for (int i = 0; i < 4; ++i)
#pragma unroll
            for (int j = 0; j < 4; ++j)
                acc[i][j] = __builtin_amdgcn_mfma_f32_16x16x32_bf16(a[i], b[j], acc[i][j], 0, 0, 0);
            __builtin_amdgcn_s_setprio(0);
        }
        if (t + 1 < NT) {
            if (t + 2 < NT) { asm volatile("s_waitcnt vmcnt(6)" ::: "memory"); }
            else            { asm volatile("s_waitcnt vmcnt(0)" ::: "memory"); }
            __builtin_amdgcn_s_barrier();
            __builtin_amdgcn_sched_barrier(0);
            asm volatile("" ::: "memory");
        }
        sc = sc == 2 ? 0 : sc + 1;
        ss = ss == 2 ? 0 : ss + 1;
    }

    // epilogue: C/D layout col = lane&15, row = (lane>>4)*4 + reg [m89/m91]
#pragma unroll
    for (int i = 0; i < 4; ++i)
#pragma unroll
    for (int j = 0; j < 4; ++j)
#pragma unroll
    for (int r = 0; r < 4; ++r) {
        int row = m0 + wm + i * 16 + fq * 4 + r;
        int col = n0 + wn + j * 16 + fr;
        float v = acc[i][j][r];
        if (EPI == 2) {
            v += bias[col];
            v = v > 0.f ? v : 0.f;
            ((unsigned short*)C)[(size_t)row * ldc + col] = f32_to_bf16(v);
        } else {   // 3: fp32 + bias
            ((float*)C)[(size_t)row * ldc + col] = v + bias[col];
        }
    }
}

// ---------------------------------------------------------------------------
// prep (R6, measured good): 64x64 transpose tiles, f32x4 loads / short4
// stores; 32-elems/thread xb convert. 2564 blocks.
// ---------------------------------------------------------------------------
__device__ __forceinline__ void transpose_tile64(const float* __restrict__ in,
                                                 unsigned short* __restrict__ out,
                                                 int rows, int cols, int bx, int by, int tid)
{
    __shared__ float t[64][65];
    int tx = tid & 15, ty = tid >> 4;   // 16 x 16
    int r0 = by * 64, c0 = bx * 64;
#pragma unroll
    for (int i = 0; i < 4; ++i) {
        f32x4 v = *(const f32x4*)(in + (size_t)(r0 + ty + i * 16) * cols + c0 + tx * 4);
#pragma unroll
        for (int j = 0; j < 4; ++j) t[ty + i * 16][tx * 4 + j] = v[j];
    }
    __syncthreads();
#pragma unroll
    for (int i = 0; i < 4; ++i) {
        union { short4v s; unsigned short u[4]; } o;
#pragma unroll
        for (int j = 0; j < 4; ++j) o.u[j] = f32_to_bf16(t[tx * 4 + j][ty + i * 16]);
        *(short4v*)(out + (size_t)(c0 + ty + i * 16) * rows + r0 + tx * 4) = o.s;
    }
}

__global__ __launch_bounds__(256)
void prep_kernel(const float* __restrict__ x,
                 const float* __restrict__ Wq, const float* __restrict__ Wk,
                 const float* __restrict__ Wv, const float* __restrict__ W1,
                 const float* __restrict__ W2,
                 unsigned short* __restrict__ xb, unsigned short* __restrict__ WT,
                 unsigned short* __restrict__ W1T, unsigned short* __restrict__ W2T,
                 float* __restrict__ rsum)
{
    int idx = blockIdx.x;
    int tid = threadIdx.x;
    if (idx < 1024) {
#pragma unroll
        for (int it = 0; it < 4; ++it) {
            size_t i = ((size_t)idx * 4 + it) * 2048 + (size_t)tid * 8;
            *(short8*)(xb + i) = load8_f32_as_bf16(x + i);
        }
    } else if (idx < 1792) {
        int t = idx - 1024;
        int w = t >> 8; t &= 255;
        const float* in = w == 0 ? Wq : (w == 1 ? Wk : Wv);
        transpose_tile64(in, WT + (size_t)w * 1024 * 1024, 1024, 1024,
                         t & 15, t >> 4, tid);
    } else if (idx < 2304) {
        int t = idx - 1792;                  // 512 tiles: 32 row-tiles x 16
        transpose_tile64(W1, W1T, 2048, 1024, t & 15, t >> 4, tid);
    } else if (idx < 2560) {
        int t = idx - 2304;                  // 256 tiles
        transpose_tile64(W2, W2T, 1024, 1024, t & 15, t >> 4, tid);
    } else {
        int t = idx - 2560;
        f32x4 zero = {0.f, 0.f, 0.f, 0.f};
        float* p = rsum + ((size_t)t * 256 + tid) * 8;
        *(f32x4*)p = zero;
        *(f32x4*)(p + 4) = zero;
    }
}

// ---------------------------------------------------------------------------
extern "C" void kernel_launch(void* const* d_in, const int* in_sizes, int n_in,
                              void* d_out, int out_size, void* d_ws, size_t ws_size,
                              hipStream_t stream)
{
    const float* x  = (const float*)d_in[0];   // [8192,1024]
    const float* Wq = (const float*)d_in[1];
    const float* Wk = (const float*)d_in[2];
    const float* Wv = (const float*)d_in[3];
    const float* W1 = (const float*)d_in[4];   // [2048,1024]
    const float* b1 = (const float*)d_in[5];
    const float* W2 = (const float*)d_in[6];   // [1024,1024]
    const float* b2 = (const float*)d_in[7];
    float* out = (float*)d_out;                // [8192,1024] fp32

    size_t off = 0;
    auto alloc = [&](size_t bytes) {
        char* r = (char*)d_ws + off;
        off += (bytes + 255) & ~(size_t)255;
        return r;
    };
    const size_t TOK = (size_t)8192 * 1024;    // tokens x dim
    unsigned short* WT   = (unsigned short*)alloc((size_t)3072 * 1024 * 2);
    unsigned short* W1T  = (unsigned short*)alloc((size_t)1024 * 2048 * 2);
    unsigned short* W2T  = (unsigned short*)alloc((size_t)1024 * 1024 * 2);
    unsigned short* xb   = (unsigned short*)alloc(TOK * 2);
    unsigned short* vT   = (unsigned short*)alloc((size_t)1024 * 8192 * 2); // [d][b*2048+s]
    unsigned short* attn = (unsigned short*)alloc(TOK * 2);
    float*          rsum = (float*)         alloc((size_t)4 * 2048 * 4);
    unsigned short* q    = (unsigned short*)alloc(TOK * 2);
    unsigned short* k    = (unsigned short*)alloc(TOK * 2);
    unsigned short* S    = (unsigned short*)alloc((size_t)4 * 2048 * 2048 * 2);
    unsigned short* h1   = S;                  // S dead after PV; MLP1 out aliases it
    // peak ws use: ~131 MB

    // prep: xb, WT, W1T, W2T, rsum=0 in one launch (2564 blocks, vectorized)
    prep_kernel<<<2564, 256, 0, stream>>>(x, Wq, Wk, Wv, W1, W2, xb, WT, W1T, W2T, rsum);

    // fused q,k,vT (z<2: q,k = xb @ Wqk^T m-chunked; z==2: vT = WvT @ xb^T
    // n-chunked). 1536 blocks, 4-resident/CU. Measured 53.3 us / ~970 TF.
    gemm128<128><<<dim3(8, 64, 3), 256, 0, stream>>>(
        xb, 1024, WT, 1024, q, 1024, 1024,
        (long)1024 * 1024, (long)TOK, vT, 8192);

    // scores+softmax fused, 128-row m-tiles: P = exp(q@k^T/32 - 16) (causal),
    // rowsums -> rsum. Triangular 136/z x 4, xcd pre-permute. (R7 config.)
    gemmdb<6, 5, false><<<dim3(136, 1, 4), 256, 0, stream>>>(
        q, 1024, k, 1024, S, 2048, 1024,
        (long)2048 * 1024, (long)2048 * 1024, (long)2048 * 2048, rsum, 2048, 0.03125f);

    // attn = (P @ v) / rsum[row]  (kend = m0+128; SWIZ=7 z-per-xcd-pair,
    // balanced m-sets, grid (8,16,4)). (R7 config.)
    gemmdb<4, 7, true><<<dim3(8, 16, 4), 256, 0, stream>>>(
        S, 2048, vT, 8192, attn, 1024, 2048,
        (long)2048 * 2048, (long)2048, (long)2048 * 1024, rsum, 2048, 0.f);

    // MLP1: h1 = relu([attn | x] @ W1 + b1), split-A concat trick.
    // gemm8p 256 blocks = 1/CU exact, uniform K=2048 (R2-measured regime).
    gemm8p<2, 2><<<dim3(8, 32, 1), 512, 0, stream>>>(
        attn, xb, 1024, 1024, 1024, W1T, 2048, h1, 1024, 2048, b1);

    // MLP2: out = h1 @ W2 + b2 (fp32 to d_out). gemm8p 256 blocks = 1/CU.
    gemm8p<0, 3><<<dim3(8, 32, 1), 512, 0, stream>>>(
        h1, nullptr, 1024, 0, 0, W2T, 1024, out, 1024, 1024, b2);
}

// Round 10
// 276.495 us; speedup vs baseline: 1.0629x; 1.0322x over previous
//
#include <hip/hip_runtime.h>
#include <stdint.h>

typedef __attribute__((ext_vector_type(8))) short short8;
typedef __attribute__((ext_vector_type(4))) short short4v;
typedef __attribute__((ext_vector_type(4))) float f32x4;

__device__ __forceinline__ unsigned short f32_to_bf16(float f) {
    unsigned int u = __float_as_uint(f);
    u += 0x7FFFu + ((u >> 16) & 1u);   // round-to-nearest-even
    return (unsigned short)(u >> 16);
}

__device__ __forceinline__ short8 load8_f32_as_bf16(const float* __restrict__ ap) {
    f32x4 f0 = *(const f32x4*)ap;
    f32x4 f1 = *(const f32x4*)(ap + 4);
    union { short8 s; unsigned short u[8]; } cv;
#pragma unroll
    for (int t = 0; t < 4; ++t) {
        cv.u[t]     = f32_to_bf16(f0[t]);
        cv.u[t + 4] = f32_to_bf16(f1[t]);
    }
    return cv.s;
}

// async global->LDS DMA, 16B/lane; LDS dest = wave-uniform base + lane*16 (m104/m108)
__device__ __forceinline__ void gld_lds16(const void* g, void* l) {
    __builtin_amdgcn_global_load_lds(
        (const __attribute__((address_space(1))) unsigned int*)(unsigned long long)(uintptr_t)g,
        (__attribute__((address_space(3))) unsigned int*)(unsigned int)(uintptr_t)l,
        16, 0, 0);
}

// ---------------------------------------------------------------------------
// gemm128: single-buffered NT GEMM (m97 structure) -- q,k projections only.
// R10: grid dim3(8,64,2) = 1024 blocks = 4 EXACT rounds at 4/CU (the
// measured-best regime: 966 TF). vT moved into the scorevt fusion below.
// z<2: mblk = x*8+(y&7) m-chunk per XCD, nblk = y>>3.
// ---------------------------------------------------------------------------
template<int MT>
__global__ __launch_bounds__(256, 4)
void gemm128(const unsigned short* __restrict__ A,
             int lda,
             const unsigned short* __restrict__ B, int ldb,
             void* __restrict__ C, int ldc, int K,
             long bStride, long cStride)
{
    int z = blockIdx.z;
    int mblk = blockIdx.x * 8 + (blockIdx.y & 7);
    int nblk = blockIdx.y >> 3;
    int m0 = mblk * MT;
    int n0 = nblk * 128;

    const unsigned short* Ab = A;
    const unsigned short* Bb = B + (size_t)z * bStride;

    __shared__ __align__(16) short As[MT * 64];
    __shared__ __align__(16) short Bs[128 * 64];

    int tid  = threadIdx.x;
    int lane = tid & 63, wid = tid >> 6;
    constexpr int MI = MT / 32;
    int wm = (wid & 1) * (MT / 2), wn = (wid >> 1) * 64;
    int fr = lane & 15, fq = lane >> 4;
    int sw0 = ((fq    ) ^ (fr & 7)) * 16;
    int sw1 = ((fq ^ 4) ^ (fr & 7)) * 16;

    int rS = tid >> 3;
    int cS = ((tid & 7) ^ (rS & 7)) * 8;
    char* AsB = (char*)As; char* BsB = (char*)Bs;

    f32x4 acc[MI][4];
#pragma unroll
    for (int i = 0; i < MI; ++i)
#pragma unroll
    for (int j = 0; j < 4; ++j) acc[i][j] = f32x4{0.f, 0.f, 0.f, 0.f};

    for (int k0 = 0; k0 < K; k0 += 64) {
        const unsigned short* pa = Ab + (size_t)(m0 + rS) * lda + k0 + cS;
        const unsigned short* pb = Bb + (size_t)(n0 + rS) * ldb + k0 + cS;
#pragma unroll
        for (int t = 0; t < MT / 32; ++t)
            gld_lds16(pa + (size_t)(32 * t) * lda, AsB + t * 4096 + tid * 16);
#pragma unroll
        for (int t = 0; t < 4; ++t)
            gld_lds16(pb + (size_t)(32 * t) * ldb,  BsB + t * 4096 + tid * 16);
        __syncthreads();

#pragma unroll
        for (int kh = 0; kh < 2; ++kh) {
            int sw = kh ? sw1 : sw0;
            short8 a[MI], b[4];
#pragma unroll
            for (int i = 0; i < MI; ++i)
                a[i] = *(const short8*)(AsB + (wm + i * 16 + fr) * 128 + sw);
#pragma unroll
            for (int j = 0; j < 4; ++j)
                b[j] = *(const short8*)(BsB + (wn + j * 16 + fr) * 128 + sw);
#pragma unroll
            for (int i = 0; i < MI; ++i)
#pragma unroll
            for (int j = 0; j < 4; ++j)
                acc[i][j] = __builtin_amdgcn_mfma_f32_16x16x32_bf16(a[i], b[j], acc[i][j], 0, 0, 0);
        }
        __syncthreads();
    }

    // epilogue: C/D layout col = lane&15, row = (lane>>4)*4 + reg [m89/m91]
    unsigned short* Cz = (unsigned short*)C + (size_t)z * cStride;
#pragma unroll
    for (int i = 0; i < MI; ++i)
#pragma unroll
    for (int j = 0; j < 4; ++j)
#pragma unroll
    for (int r = 0; r < 4; ++r) {
        int row = m0 + wm + i * 16 + fq * 4 + r;
        int col = n0 + wn + j * 16 + fr;
        Cz[(size_t)row * ldc + col] = f32_to_bf16(acc[i][j][r]);
    }
}

// ---------------------------------------------------------------------------
// scorevt: FUSED scores + vT launch (R10). 1056 blocks = ~4.1/CU on the m97
// single-buffer body (both sub-problems: K=1024, NT=16, lda=ldb=1024).
// Rationale: scores alone is 544 blocks (2.1/CU, ~600 TF class); vT is
// independent of q,k (needs only xb, WvT) -- co-scheduling restores the
// cross-block overlap that makes the 4/CU QKV run at 966 TF (m114).
// Decode: glin < 544 -> scores: t = (glin&7)*68 + glin>>3 (bijective; each
//   XCD owns 68 contiguous tri-linear indices; xcd-pair per z -> q/k slices
//   ~L2-fit); z = t/136, tri = t%136 -> (i, j) lower-triangle 128-row tiles.
//   EPI: P = exp(qk^T/32 - 16) masked col<=row, bf16 -> S; rowsums
//   atomicAdd -> rsum (const max-shift 16: exact for ratios, s>16 ~8 sigma).
// glin >= 544 -> vT: g2 = glin-544; xcd = g2&7, idx = g2>>3: nblk =
//   xcd*8 + (idx&7) (token-chunk per XCD, 2 MB xb slice L2-resident),
//   mblk = idx>>3. A = WvT (d-rows), B = xb (token-rows), C = vT[d][tok],
//   ldc = 8192 (swapped-operand build, verbatim from the old SWIZ6 z==2).
// ---------------------------------------------------------------------------
__global__ __launch_bounds__(256, 4)
void scorevt(const unsigned short* __restrict__ q,
             const unsigned short* __restrict__ k,
             unsigned short* __restrict__ S, float* __restrict__ rsum,
             float scale,
             const unsigned short* __restrict__ WvT,
             const unsigned short* __restrict__ xb,
             unsigned short* __restrict__ vT)
{
    int glin = blockIdx.x;
    bool isV = glin >= 544;
    int z = 0, m0, n0;
    const unsigned short *Ab, *Bb;
    if (!isV) {
        int t = (glin & 7) * 68 + (glin >> 3);   // [0,544) bijective
        z = t / 136;
        int tri = t - z * 136;                   // [0,136)
        int a = (int)sqrtf(2.f * (float)tri + 1.f);
        if (a > 15) a = 15;
        while (a < 15 && ((a + 1) * (a + 2) / 2) <= tri) ++a;
        while (a > 0 && (a * (a + 1) / 2) > tri) --a;
        m0 = a * 128;
        n0 = (tri - a * (a + 1) / 2) * 128;
        Ab = q + (size_t)z * 2048 * 1024;
        Bb = k + (size_t)z * 2048 * 1024;
    } else {
        int g2 = glin - 544;                     // [0,512)
        int xcd = g2 & 7, idx = g2 >> 3;         // idx in [0,64)
        int nblk = xcd * 8 + (idx & 7);          // token-tile, chunk per XCD
        int mblk = idx >> 3;                     // d-tile in [0,8)
        m0 = mblk * 128;
        n0 = nblk * 128;
        Ab = WvT;
        Bb = xb;
    }

    __shared__ __align__(16) short As[128 * 64];
    __shared__ __align__(16) short Bs[128 * 64];

    int tid  = threadIdx.x;
    int lane = tid & 63, wid = tid >> 6;
    int wm = (wid & 1) * 64, wn = (wid >> 1) * 64;
    int fr = lane & 15, fq = lane >> 4;
    int sw0 = ((fq    ) ^ (fr & 7)) * 16;
    int sw1 = ((fq ^ 4) ^ (fr & 7)) * 16;

    int rS = tid >> 3;
    int cS = ((tid & 7) ^ (rS & 7)) * 8;
    char* AsB = (char*)As; char* BsB = (char*)Bs;

    f32x4 acc[4][4];
#pragma unroll
    for (int i = 0; i < 4; ++i)
#pragma unroll
    for (int j = 0; j < 4; ++j) acc[i][j] = f32x4{0.f, 0.f, 0.f, 0.f};

    for (int k0 = 0; k0 < 1024; k0 += 64) {      // NT = 16 uniform
        const unsigned short* pa = Ab + (size_t)(m0 + rS) * 1024 + k0 + cS;
        const unsigned short* pb = Bb + (size_t)(n0 + rS) * 1024 + k0 + cS;
#pragma unroll
        for (int t = 0; t < 4; ++t)
            gld_lds16(pa + (size_t)(32 * t) * 1024, AsB + t * 4096 + tid * 16);
#pragma unroll
        for (int t = 0; t < 4; ++t)
            gld_lds16(pb + (size_t)(32 * t) * 1024, BsB + t * 4096 + tid * 16);
        __syncthreads();

#pragma unroll
        for (int kh = 0; kh < 2; ++kh) {
            int sw = kh ? sw1 : sw0;
            short8 a[4], b[4];
#pragma unroll
            for (int i = 0; i < 4; ++i)
                a[i] = *(const short8*)(AsB + (wm + i * 16 + fr) * 128 + sw);
#pragma unroll
            for (int j = 0; j < 4; ++j)
                b[j] = *(const short8*)(BsB + (wn + j * 16 + fr) * 128 + sw);
#pragma unroll
            for (int i = 0; i < 4; ++i)
#pragma unroll
            for (int j = 0; j < 4; ++j)
                acc[i][j] = __builtin_amdgcn_mfma_f32_16x16x32_bf16(a[i], b[j], acc[i][j], 0, 0, 0);
        }
        __syncthreads();
    }

    // epilogue: C/D layout col = lane&15, row = (lane>>4)*4 + reg [m89/m91]
    if (!isV) {
        unsigned short* Cz = S + (size_t)z * 2048 * 2048;
        float* rs = rsum + (size_t)z * 2048;
#pragma unroll
        for (int i = 0; i < 4; ++i)
#pragma unroll
        for (int r = 0; r < 4; ++r) {
            int row = m0 + wm + i * 16 + fq * 4 + r;
            float s = 0.f;
#pragma unroll
            for (int j = 0; j < 4; ++j) {
                int col = n0 + wn + j * 16 + fr;
                float e = (col <= row) ? __expf(acc[i][j][r] * scale - 16.f) : 0.f;
                s += e;
                Cz[(size_t)row * 2048 + col] = f32_to_bf16(e);
            }
            s += __shfl_xor(s, 1);
            s += __shfl_xor(s, 2);
            s += __shfl_xor(s, 4);
            s += __shfl_xor(s, 8);      // reduced over the 16 fr-lanes
            if (fr == 0) atomicAdd(&rs[row], s);
        }
    } else {
#pragma unroll
        for (int i = 0; i < 4; ++i)
#pragma unroll
        for (int j = 0; j < 4; ++j)
#pragma unroll
        for (int r = 0; r < 4; ++r) {
            int row = m0 + wm + i * 16 + fq * 4 + r;     // d
            int col = n0 + wn + j * 16 + fr;             // token
            vT[(size_t)row * 8192 + col] = f32_to_bf16(acc[i][j][r]);
        }
    }
}

// ---------------------------------------------------------------------------
// gemmdb: double-buffered NT GEMM (R7/R9 config) -- PV only now.
// MT=128, BK=64, 4 waves, LDS 64 KB (2 buf), counted vmcnt(8) gate.
// SWIZ7 decode, grid MUST be (8,16,4): xcd=glin%8, z=xcd>>1 (vT slice per
// xcd-pair L2), balanced m-sets (per-XCD kend sum const). kend=min(K,m0+128).
// EPI: divide by softmax rowsum, bf16.
// ---------------------------------------------------------------------------
__global__ __launch_bounds__(256, 2)
void gemmdb(const unsigned short* __restrict__ A,
            int lda,
            const unsigned short* __restrict__ B, int ldb,
            void* __restrict__ C, int ldc, int K,
            long aStride, long bStride, long cStride,
            const float* __restrict__ bias, long biasStride)
{
    int glin = (int)blockIdx.z * 128 + (int)blockIdx.y * 8 + (int)blockIdx.x;
    int xcd = glin & 7;
    int s   = glin >> 3;                  // [0,64) per xcd
    int z = xcd >> 1;                     // batch owned by this xcd pair
    int h  = xcd & 1;
    int jm = s & 7;
    int nblk = s >> 3;                    // [0,8)
    int mblk = (jm & 1) ? (15 - h - (jm >> 1) * 2) : ((jm >> 1) * 2 + h);
    int m0 = mblk * 128;
    int n0 = nblk * 128;

    const unsigned short* Ab = A + (size_t)z * aStride;
    const unsigned short* Bb = B + (size_t)z * bStride;

    __shared__ __align__(16) char lds[65536];   // 2 x [A 16K | B 16K]

    int tid  = threadIdx.x;
    int lane = tid & 63, wid = tid >> 6;
    int wm = (wid & 1) * 64, wn = (wid >> 1) * 64;
    int fr = lane & 15, fq = lane >> 4;
    int sw0 = ((fq    ) ^ (fr & 7)) * 16;
    int sw1 = ((fq ^ 4) ^ (fr & 7)) * 16;

    int rS = tid >> 3;                       // 0..31
    int cS = ((tid & 7) ^ (rS & 7)) * 8;     // swizzled source chunk (k elems)

    int kend = min(K, m0 + 128);
    int NT = kend >> 6;

    f32x4 acc[4][4];
#pragma unroll
    for (int i = 0; i < 4; ++i)
#pragma unroll
    for (int j = 0; j < 4; ++j) acc[i][j] = f32x4{0.f, 0.f, 0.f, 0.f};

    auto STAGE = [&](int kt) {               // 8 gld_lds per thread
        char* dst = lds + (kt & 1) * 32768;
        const unsigned short* pa = Ab + (size_t)(m0 + rS) * lda + (kt << 6) + cS;
        const unsigned short* pb = Bb + (size_t)(n0 + rS) * ldb + (kt << 6) + cS;
#pragma unroll
        for (int u = 0; u < 4; ++u)
            gld_lds16(pa + (size_t)(32 * u) * lda, dst + u * 4096 + tid * 16);
#pragma unroll
        for (int u = 0; u < 4; ++u)
            gld_lds16(pb + (size_t)(32 * u) * ldb, dst + 16384 + u * 4096 + tid * 16);
    };

    STAGE(0);
    for (int t = 0; t < NT; ++t) {
        if (t + 1 < NT) {
            STAGE(t + 1);                    // 16 outstanding; wait oldest 8
            asm volatile("s_waitcnt vmcnt(8)" ::: "memory");
        } else {
            asm volatile("s_waitcnt vmcnt(0)" ::: "memory");
        }
        __builtin_amdgcn_s_barrier();        // all waves' tile-t loads landed
        __builtin_amdgcn_sched_barrier(0);
        const char* AsB = (const char*)lds + (t & 1) * 32768;
        const char* BsB = AsB + 16384;
#pragma unroll
        for (int kh = 0; kh < 2; ++kh) {
            int sw = kh ? sw1 : sw0;
            short8 a[4], b[4];
#pragma unroll
            for (int i = 0; i < 4; ++i)
                a[i] = *(const short8*)(AsB + (wm + i * 16 + fr) * 128 + sw);
#pragma unroll
            for (int j = 0; j < 4; ++j)
                b[j] = *(const short8*)(BsB + (wn + j * 16 + fr) * 128 + sw);
            __builtin_amdgcn_s_setprio(1);
#pragma unroll
            for (int i = 0; i < 4; ++i)
#pragma unroll
            for (int j = 0; j < 4; ++j)
                acc[i][j] = __builtin_amdgcn_mfma_f32_16x16x32_bf16(a[i], b[j], acc[i][j], 0, 0, 0);
            __builtin_amdgcn_s_setprio(0);
        }
        __builtin_amdgcn_s_barrier();        // WAR: next iter stages this buf
        __builtin_amdgcn_sched_barrier(0);
        asm volatile("" ::: "memory");
    }

    // epilogue: divide by rowsum
    unsigned short* Cz = (unsigned short*)C + (size_t)z * cStride;
#pragma unroll
    for (int i = 0; i < 4; ++i)
#pragma unroll
    for (int r = 0; r < 4; ++r) {
        int row = m0 + wm + i * 16 + fq * 4 + r;
        float inv = 1.f / bias[z * biasStride + row];
#pragma unroll
        for (int j = 0; j < 4; ++j) {
            int col = n0 + wn + j * 16 + fr;
            Cz[(size_t)row * ldc + col] = f32_to_bf16(acc[i][j][r] * inv);
        }
    }
}

// ---------------------------------------------------------------------------
// gemm8p: 256x128-tile ring-pipelined NT GEMM (3-slot LDS ring, 144 KB,
// 8 waves, counted vmcnt(6)) -- MLPs ONLY (uniform-K exactly-1-round
// 256-block grids, its only proven regime). SWIZ=1 xcd-m-chunk.
// EPI 2 relu(+bias) bf16 | 3 +bias fp32. AMODE 2: A->A2 at k>=ksplit.
// ---------------------------------------------------------------------------
template<int AMODE, int EPI>
__global__ __launch_bounds__(512, 2)
void gemm8p(const unsigned short* __restrict__ A, const unsigned short* __restrict__ A2,
            int lda, int lda2, int ksplit,
            const unsigned short* __restrict__ B, int ldb,
            void* __restrict__ C, int ldc, int K,
            const float* __restrict__ bias)
{
    int lin = blockIdx.y * gridDim.x + blockIdx.x;
    int xcd = lin & 7, idx = lin >> 3;
    int mch = (int)gridDim.y >> 3;           // (8,32) -> 4 m-tiles per XCD
    int mblk = xcd * mch + idx % mch;
    int nblk = idx / mch;
    int m0 = mblk * 256, n0 = nblk * 128;

    constexpr int TILE = 49152;              // 32K A + 16K B per ring slot
    __shared__ __align__(16) char lds[3 * TILE];   // 144 KB

    int tid  = threadIdx.x;
    int lane = tid & 63, wid = tid >> 6;
    int wm = (wid & 3) * 64, wn = (wid >> 2) * 64;
    int fr = lane & 15, fq = lane >> 4;
    int sw0 = ((fq    ) ^ (fr & 7)) * 16;
    int sw1 = ((fq ^ 4) ^ (fr & 7)) * 16;

    int rS = tid >> 3;                       // 0..63
    int cS = ((tid & 7) ^ (rS & 7)) * 8;

    int NT = K >> 6;                         // 16 or 32 here

    f32x4 acc[4][4];
#pragma unroll
    for (int i = 0; i < 4; ++i)
#pragma unroll
    for (int j = 0; j < 4; ++j) acc[i][j] = f32x4{0.f, 0.f, 0.f, 0.f};

    auto STAGE = [&](int t, int slot) {      // 6 gld_lds per thread
        int k0 = t << 6;
        char* dst = lds + slot * TILE;
        const unsigned short* Asrc = A; int koff = k0, ldax = lda;
        if (AMODE == 2 && k0 >= ksplit) { Asrc = A2; koff = k0 - ksplit; ldax = lda2; }
        const unsigned short* pa = Asrc + (size_t)(m0 + rS) * ldax + koff + cS;
        const unsigned short* pb = B    + (size_t)(n0 + rS) * ldb  + k0   + cS;
#pragma unroll
        for (int u = 0; u < 4; ++u)
            gld_lds16(pa + (size_t)(64 * u) * ldax, dst + u * 8192 + tid * 16);
#pragma unroll
        for (int u = 0; u < 2; ++u)
            gld_lds16(pb + (size_t)(64 * u) * ldb, dst + 32768 + u * 8192 + tid * 16);
    };

    // prologue: 2 tiles in flight, wait only for tile 0 (oldest 6 of 12)
    STAGE(0, 0);
    STAGE(1, 1);
    asm volatile("s_waitcnt vmcnt(6)" ::: "memory");
    __builtin_amdgcn_s_barrier();
    __builtin_amdgcn_sched_barrier(0);
    asm volatile("" ::: "memory");

    int sc = 0, ss = 2;                      // compute slot, stage slot
    for (int t = 0; t < NT; ++t) {
        if (t + 2 < NT) STAGE(t + 2, ss);    // slot staged == slot read at t-1
        const char* AsB = (const char*)(lds + sc * TILE);
        const char* BsB = AsB + 32768;
#pragma unroll
        for (int kh = 0; kh < 2; ++kh) {
            int sw = kh ? sw1 : sw0;
            short8 a[4], b[4];
#pragma unroll
            for (int i = 0; i < 4; ++i)
                a[i] = *(const short8*)(AsB + (wm + i * 16 + fr) * 128 + sw);
#pragma unroll
            for (int j = 0; j < 4; ++j)
                b[j] = *(const short8*)(BsB + (wn + j * 16 + fr) * 128 + sw);
            __builtin_amdgcn_s_setprio(1);
#pragma unroll
            for (int i = 0; i < 4; ++i)
#pragma unroll
            for (int j = 0; j < 4; ++j)
                acc[i][j] = __builtin_amdgcn_mfma_f32_16x16x32_bf16(a[i], b[j], acc[i][j], 0, 0, 0);
            __builtin_amdgcn_s_setprio(0);
        }
        if (t + 1 < NT) {
            if (t + 2 < NT) { asm volatile("s_waitcnt vmcnt(6)" ::: "memory"); }
            else            { asm volatile("s_waitcnt vmcnt(0)" ::: "memory"); }
            __builtin_amdgcn_s_barrier();
            __builtin_amdgcn_sched_barrier(0);
            asm volatile("" ::: "memory");
        }
        sc = sc == 2 ? 0 : sc + 1;
        ss = ss == 2 ? 0 : ss + 1;
    }

    // epilogue: C/D layout col = lane&15, row = (lane>>4)*4 + reg [m89/m91]
#pragma unroll
    for (int i = 0; i < 4; ++i)
#pragma unroll
    for (int j = 0; j < 4; ++j)
#pragma unroll
    for (int r = 0; r < 4; ++r) {
        int row = m0 + wm + i * 16 + fq * 4 + r;
        int col = n0 + wn + j * 16 + fr;
        float v = acc[i][j][r];
        if (EPI == 2) {
            v += bias[col];
            v = v > 0.f ? v : 0.f;
            ((unsigned short*)C)[(size_t)row * ldc + col] = f32_to_bf16(v);
        } else {   // 3: fp32 + bias
            ((float*)C)[(size_t)row * ldc + col] = v + bias[col];
        }
    }
}

// ---------------------------------------------------------------------------
// prep (R6, measured good): 64x64 transpose tiles, f32x4 loads / short4
// stores; 32-elems/thread xb convert. 2564 blocks.
// ---------------------------------------------------------------------------
__device__ __forceinline__ void transpose_tile64(const float* __restrict__ in,
                                                 unsigned short* __restrict__ out,
                                                 int rows, int cols, int bx, int by, int tid)
{
    __shared__ float t[64][65];
    int tx = tid & 15, ty = tid >> 4;   // 16 x 16
    int r0 = by * 64, c0 = bx * 64;
#pragma unroll
    for (int i = 0; i < 4; ++i) {
        f32x4 v = *(const f32x4*)(in + (size_t)(r0 + ty + i * 16) * cols + c0 + tx * 4);
#pragma unroll
        for (int j = 0; j < 4; ++j) t[ty + i * 16][tx * 4 + j] = v[j];
    }
    __syncthreads();
#pragma unroll
    for (int i = 0; i < 4; ++i) {
        union { short4v s; unsigned short u[4]; } o;
#pragma unroll
        for (int j = 0; j < 4; ++j) o.u[j] = f32_to_bf16(t[tx * 4 + j][ty + i * 16]);
        *(short4v*)(out + (size_t)(c0 + ty + i * 16) * rows + r0 + tx * 4) = o.s;
    }
}

__global__ __launch_bounds__(256)
void prep_kernel(const float* __restrict__ x,
                 const float* __restrict__ Wq, const float* __restrict__ Wk,
                 const float* __restrict__ Wv, const float* __restrict__ W1,
                 const float* __restrict__ W2,
                 unsigned short* __restrict__ xb, unsigned short* __restrict__ WT,
                 unsigned short* __restrict__ W1T, unsigned short* __restrict__ W2T,
                 float* __restrict__ rsum)
{
    int idx = blockIdx.x;
    int tid = threadIdx.x;
    if (idx < 1024) {
#pragma unroll
        for (int it = 0; it < 4; ++it) {
            size_t i = ((size_t)idx * 4 + it) * 2048 + (size_t)tid * 8;
            *(short8*)(xb + i) = load8_f32_as_bf16(x + i);
        }
    } else if (idx < 1792) {
        int t = idx - 1024;
        int w = t >> 8; t &= 255;
        const float* in = w == 0 ? Wq : (w == 1 ? Wk : Wv);
        transpose_tile64(in, WT + (size_t)w * 1024 * 1024, 1024, 1024,
                         t & 15, t >> 4, tid);
    } else if (idx < 2304) {
        int t = idx - 1792;                  // 512 tiles: 32 row-tiles x 16
        transpose_tile64(W1, W1T, 2048, 1024, t & 15, t >> 4, tid);
    } else if (idx < 2560) {
        int t = idx - 2304;                  // 256 tiles
        transpose_tile64(W2, W2T, 1024, 1024, t & 15, t >> 4, tid);
    } else {
        int t = idx - 2560;
        f32x4 zero = {0.f, 0.f, 0.f, 0.f};
        float* p = rsum + ((size_t)t * 256 + tid) * 8;
        *(f32x4*)p = zero;
        *(f32x4*)(p + 4) = zero;
    }
}

// ---------------------------------------------------------------------------
extern "C" void kernel_launch(void* const* d_in, const int* in_sizes, int n_in,
                              void* d_out, int out_size, void* d_ws, size_t ws_size,
                              hipStream_t stream)
{
    const float* x  = (const float*)d_in[0];   // [8192,1024]
    const float* Wq = (const float*)d_in[1];
    const float* Wk = (const float*)d_in[2];
    const float* Wv = (const float*)d_in[3];
    const float* W1 = (const float*)d_in[4];   // [2048,1024]
    const float* b1 = (const float*)d_in[5];
    const float* W2 = (const float*)d_in[6];   // [1024,1024]
    const float* b2 = (const float*)d_in[7];
    float* out = (float*)d_out;                // [8192,1024] fp32

    size_t off = 0;
    auto alloc = [&](size_t bytes) {
        char* r = (char*)d_ws + off;
        off += (bytes + 255) & ~(size_t)255;
        return r;
    };
    const size_t TOK = (size_t)8192 * 1024;    // tokens x dim
    unsigned short* WT   = (unsigned short*)alloc((size_t)3072 * 1024 * 2);
    unsigned short* W1T  = (unsigned short*)alloc((size_t)1024 * 2048 * 2);
    unsigned short* W2T  = (unsigned short*)alloc((size_t)1024 * 1024 * 2);
    unsigned short* xb   = (unsigned short*)alloc(TOK * 2);
    unsigned short* vT   = (unsigned short*)alloc((size_t)1024 * 8192 * 2); // [d][b*2048+s]
    unsigned short* attn = (unsigned short*)alloc(TOK * 2);
    float*          rsum = (float*)         alloc((size_t)4 * 2048 * 4);
    unsigned short* q    = (unsigned short*)alloc(TOK * 2);
    unsigned short* k    = (unsigned short*)alloc(TOK * 2);
    unsigned short* S    = (unsigned short*)alloc((size_t)4 * 2048 * 2048 * 2);
    unsigned short* h1   = S;                  // S dead after PV; MLP1 out aliases it
    // peak ws use: ~131 MB

    // prep: xb, WT, W1T, W2T, rsum=0 in one launch (2564 blocks, vectorized)
    prep_kernel<<<2564, 256, 0, stream>>>(x, Wq, Wk, Wv, W1, W2, xb, WT, W1T, W2T, rsum);

    // q,k = xb @ Wq^T / Wk^T: 1024 blocks = 4 EXACT rounds at 4/CU
    // (vT removed from this launch -- it rides with scores below).
    gemm128<128><<<dim3(8, 64, 2), 256, 0, stream>>>(
        xb, 1024, WT, 1024, q, 1024, 1024,
        (long)1024 * 1024, (long)TOK);

    // FUSED scores+vT: 544 tri-blocks (P = exp(q@k^T/32 - 16) causal,
    // rowsums->rsum) + 512 vT blocks (vT = WvT @ xb^T) = 1056 blocks
    // ~4.1/CU co-resident.
    scorevt<<<1056, 256, 0, stream>>>(
        q, k, S, rsum, 0.03125f, WT + (size_t)2 * 1024 * 1024, xb, vT);

    // attn = (P @ v) / rsum[row]  (kend = m0+128; SWIZ7 z-per-xcd-pair,
    // balanced m-sets, grid (8,16,4)). (R7/R9 config.)
    gemmdb<<<dim3(8, 16, 4), 256, 0, stream>>>(
        S, 2048, vT, 8192, attn, 1024, 2048,
        (long)2048 * 2048, (long)2048, (long)2048 * 1024, rsum, 2048);

    // MLP1: h1 = relu([attn | x] @ W1 + b1), split-A concat trick.
    // gemm8p 256 blocks = 1/CU exact, uniform K=2048. (R9 config.)
    gemm8p<2, 2><<<dim3(8, 32, 1), 512, 0, stream>>>(
        attn, xb, 1024, 1024, 1024, W1T, 2048, h1, 1024, 2048, b1);

    // MLP2: out = h1 @ W2 + b2 (fp32 to d_out). gemm8p 256 blocks = 1/CU.
    gemm8p<0, 3><<<dim3(8, 32, 1), 512, 0, stream>>>(
        h1, nullptr, 1024, 0, 0, W2T, 1024, out, 1024, 1024, b2);
}